// Round 5
// baseline (20640.723 us; speedup 1.0000x reference)
//
#include <hip/hip_runtime.h>
#include <hip/hip_bf16.h>

typedef long long i64;

// ---- output element offsets (FLOAT32 elements — d_out is float*) ----
static constexpr i64 OUT_POLICY = 0;
static constexpr i64 OUT_VALUE  = 46336;
static constexpr i64 OUT_ZE0    = 46464;
static constexpr i64 OUT_ZE1    = 1525120;
static constexpr i64 OUT_ZE2    = 1590656;
static constexpr i64 OUT_ZQ0    = 1656192;
static constexpr i64 OUT_ZQ1    = 3134848;
static constexpr i64 OUT_ZQ2    = 3200384;
static constexpr i64 OUT_K0     = 3265920;
static constexpr i64 OUT_K1     = 3312128;
static constexpr i64 OUT_K2     = 3313152;
static constexpr i64 OUT_ZQL0   = 3314176;
static constexpr i64 OUT_ZQL1   = 4792832;
static constexpr i64 OUT_ZQL2   = 4858368;
static constexpr i64 OUT_EM0    = 4923904;
static constexpr i64 OUT_EM1    = 6402560;
static constexpr i64 OUT_EM2    = 6468096;
static constexpr i64 OUT_TOTAL  = 6533632;

// =============== conv 3x3 SAME, NCHW, f32, no bias (BN cancels it) ===============
template<int CIN, int TCO, int CHUNK>
__global__ __launch_bounds__(384)
void conv3x3_k(const float* __restrict__ in, const float* __restrict__ w,
               float* __restrict__ out, int cout)
{
    __shared__ float tile[CHUNK][441];
    const int n   = blockIdx.x;
    const int co0 = blockIdx.y * TCO;
    const int tid = threadIdx.x;
    const bool act = tid < 361;
    const int y = tid / 19, x = tid % 19;
    float acc[TCO];
#pragma unroll
    for (int i = 0; i < TCO; i++) acc[i] = 0.f;

    for (int ci0 = 0; ci0 < CIN; ci0 += CHUNK) {
        __syncthreads();
        for (int i = tid; i < CHUNK * 441; i += 384) {
            int p = i / 441, r = i - p * 441;
            int yy = r / 21, xx = r - yy * 21;
            int iy = yy - 1, ix = xx - 1;
            float v = 0.f;
            if (iy >= 0 && iy < 19 && ix >= 0 && ix < 19)
                v = in[((i64)n * CIN + ci0 + p) * 361 + iy * 19 + ix];
            tile[p][r] = v;
        }
        __syncthreads();
        if (act) {
#pragma unroll 1
            for (int p = 0; p < CHUNK; p++) {
                float t[9];
#pragma unroll
                for (int dy = 0; dy < 3; dy++)
#pragma unroll
                    for (int dx = 0; dx < 3; dx++)
                        t[dy * 3 + dx] = tile[p][(y + dy) * 21 + x + dx];
                const float* wp = w + ((i64)co0 * CIN + ci0 + p) * 9;
#pragma unroll
                for (int co = 0; co < TCO; co++) {
                    const float* wc = wp + (i64)co * CIN * 9;
                    float a = acc[co];
#pragma unroll
                    for (int q = 0; q < 9; q++) a = fmaf(t[q], wc[q], a);
                    acc[co] = a;
                }
            }
        }
    }
    if (act) {
#pragma unroll
        for (int co = 0; co < TCO; co++)
            out[((i64)n * cout + co0 + co) * 361 + tid] = acc[co];
    }
}

// =============== BN batch-stats -> scale/shift ===============
__global__ __launch_bounds__(256)
void bnstats_k(const float* __restrict__ x, const float* __restrict__ g,
               const float* __restrict__ b, float* __restrict__ scale,
               float* __restrict__ shift, int C)
{
    const int c = blockIdx.x;
    float s = 0.f, s2 = 0.f;
    for (int n = 0; n < 128; n++) {
        const float* p = x + ((i64)n * C + c) * 361;
        for (int i = threadIdx.x; i < 361; i += 256) {
            float v = p[i]; s += v; s2 += v * v;
        }
    }
    __shared__ float rs[4], rq[4];
    for (int o = 32; o > 0; o >>= 1) { s += __shfl_down(s, o); s2 += __shfl_down(s2, o); }
    int lane = threadIdx.x & 63, wid = threadIdx.x >> 6;
    if (lane == 0) { rs[wid] = s; rq[wid] = s2; }
    __syncthreads();
    if (threadIdx.x == 0) {
        float S = rs[0] + rs[1] + rs[2] + rs[3];
        float Q = rq[0] + rq[1] + rq[2] + rq[3];
        const float inv = 1.f / 46208.f;
        float m  = S * inv;
        float var = Q * inv - m * m;
        float sc = g[c] * rsqrtf(var + 1e-5f);
        scale[c] = sc;
        shift[c] = b[c] - m * sc;
    }
}

// =============== BN apply variants (ws-only) ===============
__global__ void bn_relu_k(float* __restrict__ x, const float* __restrict__ scale,
                          const float* __restrict__ shift, int C, int total)
{
    for (int i = blockIdx.x * blockDim.x + threadIdx.x; i < total; i += gridDim.x * blockDim.x) {
        int c = (i / 361) % C;
        float v = fmaf(x[i], scale[c], shift[c]);
        x[i] = v > 0.f ? v : 0.f;
    }
}

__global__ void bn_add_relu_slice_k(float* __restrict__ xa, const float* __restrict__ xc,
                                    const float* __restrict__ scale, const float* __restrict__ shift,
                                    int cbase, int total)
{
    for (int i = blockIdx.x * blockDim.x + threadIdx.x; i < total; i += gridDim.x * blockDim.x) {
        int s = i % 361;
        int t = i / 361;
        int ch = t % 64;
        int n = t / 64;
        i64 ai = ((i64)n * 256 + cbase + ch) * 361 + s;
        float v = xa[ai] + fmaf(xc[i], scale[ch], shift[ch]);
        xa[ai] = v > 0.f ? v : 0.f;
    }
}

__global__ void bn_tanh_ws_k(const float* __restrict__ x, const float* __restrict__ scale,
                             const float* __restrict__ shift, float* __restrict__ zf, int total)
{
    for (int i = blockIdx.x * blockDim.x + threadIdx.x; i < total; i += gridDim.x * blockDim.x) {
        int c = (i / 361) & 31;
        zf[i] = tanhf(fmaf(x[i], scale[c], shift[c]));
    }
}

// =============== codebook prep ===============
__global__ void prep_k(const float* __restrict__ E0, const float* __restrict__ E1,
                       const float* __restrict__ E2,
                       float* __restrict__ ee0, float* __restrict__ ee1, float* __restrict__ ee2,
                       float* __restrict__ cm0, float* __restrict__ cm1, float* __restrict__ cm2)
{
    int t = threadIdx.x;
    if (blockIdx.x == 0) {
        float s = 0.f; const float* e = E0 + (i64)t * 32;
        for (int d = 0; d < 32; d++) s += e[d] * e[d];
        ee0[t] = s;
    } else if (blockIdx.x == 1) {
        float s = 0.f; const float* e = E1 + (i64)t * 64;
        for (int d = 0; d < 64; d++) s += e[d] * e[d];
        ee1[t] = s;
    } else if (blockIdx.x == 2) {
        float s = 0.f; const float* e = E2 + (i64)t * 64;
        for (int d = 0; d < 64; d++) s += e[d] * e[d];
        ee2[t] = s;
    } else {
        if (t < 32) {
            float s = 0.f; for (int k = 0; k < 512; k++) s += E0[k * 32 + t];
            cm0[t] = s * (1.f / 512.f);
        } else if (t >= 64 && t < 128) {
            int d = t - 64; float s = 0.f; for (int k = 0; k < 512; k++) s += E1[k * 64 + d];
            cm1[d] = s * (1.f / 512.f);
        } else if (t >= 128 && t < 192) {
            int d = t - 128; float s = 0.f; for (int k = 0; k < 512; k++) s += E2[k * 64 + d];
            cm2[d] = s * (1.f / 512.f);
        }
    }
}

// =============== VQ kernels (32 KB LDS, multi-pass staging) ===============
__global__ __launch_bounds__(256)
void vq0_k(const float* __restrict__ z, const float* __restrict__ E,
           const float* __restrict__ ee, float* __restrict__ zqf, int* __restrict__ ki)
{
    __shared__ float Es[256 * 32];
    int row = blockIdx.x * 256 + threadIdx.x;
    const bool live = row < 46208;
    const float* zp = z + (i64)(live ? row : 0) * 32;
    float zv[32]; float zz = 0.f;
#pragma unroll
    for (int d = 0; d < 32; d++) { float v = zp[d]; zv[d] = v; zz += v * v; }
    float best = 3.4e38f; int bk = 0;
    for (int h = 0; h < 2; h++) {
        __syncthreads();
        for (int i = threadIdx.x; i < 256 * 32; i += 256) Es[i] = E[h * 8192 + i];
        __syncthreads();
        for (int k = 0; k < 256; k++) {
            const float* e = Es + k * 32;
            float dot = 0.f;
#pragma unroll
            for (int d = 0; d < 32; d++) dot = fmaf(zv[d], e[d], dot);
            float dist = (zz + ee[h * 256 + k]) - 2.f * dot;
            if (dist < best) { best = dist; bk = h * 256 + k; }
        }
    }
    if (live) {
        ki[row] = bk;
        const float* eb = E + (i64)bk * 32;
#pragma unroll
        for (int d = 0; d < 32; d++) zqf[(i64)row * 32 + d] = eb[d];
    }
}

__global__ __launch_bounds__(256)
void vq64_k(const float* __restrict__ z, const float* __restrict__ E,
            const float* __restrict__ ee, float* __restrict__ zqf, int* __restrict__ ki)
{
    __shared__ float Es[128 * 64];
    int row = blockIdx.x * 256 + threadIdx.x;
    const float* zp = z + (i64)row * 64;
    float zv[64]; float zz = 0.f;
#pragma unroll
    for (int d = 0; d < 64; d++) { float v = zp[d]; zv[d] = v; zz += v * v; }
    float best = 3.4e38f; int bk = 0;
    for (int h = 0; h < 4; h++) {
        __syncthreads();
        for (int i = threadIdx.x; i < 128 * 64; i += 256) Es[i] = E[(i64)h * 8192 + i];
        __syncthreads();
        for (int k = 0; k < 128; k++) {
            const float* e = Es + k * 64;
            float dot = 0.f;
#pragma unroll
            for (int d = 0; d < 64; d++) dot = fmaf(zv[d], e[d], dot);
            float dist = (zz + ee[h * 128 + k]) - 2.f * dot;
            if (dist < best) { best = dist; bk = h * 128 + k; }
        }
    }
    ki[row] = bk;
    const float* eb = E + (i64)bk * 64;
#pragma unroll
    for (int d = 0; d < 64; d++) zqf[(i64)row * 64 + d] = eb[d];
}

// =============== split-K GEMM ===============
__global__ __launch_bounds__(256)
void gemm_part_k(const float* __restrict__ A, const float* __restrict__ W,
                 float* __restrict__ part, int K, int N, int kchunk)
{
    __shared__ float As[128][17];
    __shared__ float Ws[16][64];
    const int n0 = blockIdx.x * 64;
    const int ks = blockIdx.y;
    const int kb0  = ks * kchunk;
    const int kend = min(K, kb0 + kchunk);
    const int tid = threadIdx.x;
    const int tn = tid & 15, tm = tid >> 4;
    float acc[8][4];
#pragma unroll
    for (int i = 0; i < 8; i++)
#pragma unroll
        for (int j = 0; j < 4; j++) acc[i][j] = 0.f;

    for (int kb = kb0; kb < kend; kb += 16) {
        __syncthreads();
        for (int i = tid; i < 2048; i += 256) {
            int m = i >> 4, kk = i & 15;
            int k = kb + kk;
            As[m][kk] = (k < kend) ? A[(i64)m * K + k] : 0.f;
        }
        for (int i = tid; i < 1024; i += 256) {
            int kk = i >> 6, nl = i & 63;
            int k = kb + kk, n = n0 + nl;
            Ws[kk][nl] = (k < kend && n < N) ? W[(i64)k * N + n] : 0.f;
        }
        __syncthreads();
#pragma unroll
        for (int kk = 0; kk < 16; kk++) {
            float av[8], wv[4];
#pragma unroll
            for (int i = 0; i < 8; i++) av[i] = As[tm * 8 + i][kk];
#pragma unroll
            for (int j = 0; j < 4; j++) wv[j] = Ws[kk][tn * 4 + j];
#pragma unroll
            for (int i = 0; i < 8; i++)
#pragma unroll
                for (int j = 0; j < 4; j++) acc[i][j] = fmaf(av[i], wv[j], acc[i][j]);
        }
    }
#pragma unroll
    for (int i = 0; i < 8; i++) {
        int m = tm * 8 + i;
#pragma unroll
        for (int j = 0; j < 4; j++) {
            int n = n0 + tn * 4 + j;
            if (n < N) part[((i64)ks * 128 + m) * N + n] = acc[i][j];
        }
    }
}

__global__ void combine_k(const float* __restrict__ part, const float* __restrict__ bias,
                          float* __restrict__ of, int MN, int N, int ksplit, int act)
{
    for (int i = blockIdx.x * blockDim.x + threadIdx.x; i < MN; i += gridDim.x * blockDim.x) {
        float s = 0.f;
        for (int t = 0; t < ksplit; t++) s += part[(i64)t * MN + i];
        s += bias[i % N];
        if (act == 1) s = s > 0.f ? s : 0.f;
        else if (act == 2) s = tanhf(s);
        of[i] = s;
    }
}

__global__ void blend_k(const float* __restrict__ q, const float* __restrict__ d,
                        const float* __restrict__ hu, int col, float* __restrict__ o,
                        int per_b, int total)
{
    for (int i = blockIdx.x * blockDim.x + threadIdx.x; i < total; i += gridDim.x * blockDim.x) {
        float u = hu[(i / per_b) * 2 + col];
        o[i] = u * q[i] + (1.f - u) * d[i];
    }
}

__global__ __launch_bounds__(256)
void value_k(const float* __restrict__ x, const float* __restrict__ w,
             const float* __restrict__ b, float* __restrict__ valf)
{
    int m = blockIdx.x;
    float s = 0.f;
    const float* xp = x + (i64)m * 11552;
    for (int k = threadIdx.x; k < 11552; k += 256) s = fmaf(xp[k], w[k], s);
    for (int o = 32; o > 0; o >>= 1) s += __shfl_down(s, o);
    __shared__ float r[4];
    int lane = threadIdx.x & 63, wid = threadIdx.x >> 6;
    if (lane == 0) r[wid] = s;
    __syncthreads();
    if (threadIdx.x == 0)
        valf[m] = tanhf(r[0] + r[1] + r[2] + r[3] + b[0]);
}

// =============== emit phase (d_out is FLOAT32) ===============
__global__ void emit_f32_k(const float* __restrict__ src, float* __restrict__ out, i64 off, int n)
{
    for (int i = blockIdx.x * blockDim.x + threadIdx.x; i < n; i += gridDim.x * blockDim.x)
        out[off + i] = src[i];
}

__global__ void emit_k_k(const int* __restrict__ ki, float* __restrict__ out, i64 off, int n)
{
    for (int i = blockIdx.x * blockDim.x + threadIdx.x; i < n; i += gridDim.x * blockDim.x)
        out[off + i] = (float)ki[i];
}

__global__ void emit_em_k(const float* __restrict__ cm, float* __restrict__ out, i64 off,
                          int D, int SPL, int total)
{
    for (int i = blockIdx.x * blockDim.x + threadIdx.x; i < total; i += gridDim.x * blockDim.x) {
        int c = (i / SPL) % D;
        out[off + i] = cm[c];
    }
}

// =============== guard markers ===============
__global__ void marker_k(float* __restrict__ out, int code)
{
    if (threadIdx.x < 64) out[threadIdx.x] = 3000.f + 100.f * code;
}

__global__ void sentinel_k(float* __restrict__ out)
{
    if (threadIdx.x < 128) out[OUT_VALUE + threadIdx.x] = 2000.0f;
}

// ===================== host launch =====================
extern "C" void kernel_launch(void* const* d_in, const int* in_sizes, int n_in,
                              void* d_out, int out_size, void* d_ws, size_t ws_size,
                              hipStream_t stream)
{
    float* out = (float*)d_out;

    int bad = -1;
    if (out_size != (int)OUT_TOTAL) bad = 0;
    else if (n_in != 41) bad = 1;
    else if (in_sizes[0] != 128 * 18 * 361) bad = 2;
    else if (in_sizes[21] != 11552 * 256) bad = 3;
    if (bad >= 0) { marker_k<<<1, 64, 0, stream>>>(out, bad); return; }

    const float* obs   = (const float*)d_in[0];
    const float* hier  = (const float*)d_in[1];
    const float* c0w   = (const float*)d_in[2];
    const float* bn0g  = (const float*)d_in[4];
    const float* bn0b  = (const float*)d_in[5];
    const float* rb1w  = (const float*)d_in[6];
    const float* rbn1g = (const float*)d_in[8];
    const float* rbn1b = (const float*)d_in[9];
    const float* rb2w  = (const float*)d_in[10];
    const float* rbn2g = (const float*)d_in[12];
    const float* rbn2b = (const float*)d_in[13];
    const float* c2w   = (const float*)d_in[14];
    const float* bn2g  = (const float*)d_in[16];
    const float* bn2b  = (const float*)d_in[17];
    const float* E0    = (const float*)d_in[18];
    const float* E1    = (const float*)d_in[19];
    const float* E2    = (const float*)d_in[20];
    const float* fc1w  = (const float*)d_in[21]; const float* fc1b  = (const float*)d_in[22];
    const float* fc2w  = (const float*)d_in[23]; const float* fc2b  = (const float*)d_in[24];
    const float* h2fw  = (const float*)d_in[25]; const float* h2fb  = (const float*)d_in[26];
    const float* h2f2w = (const float*)d_in[27]; const float* h2f2b = (const float*)d_in[28];
    const float* h2f3w = (const float*)d_in[29]; const float* h2f3b = (const float*)d_in[30];
    const float* h2f4w = (const float*)d_in[31]; const float* h2f4b = (const float*)d_in[32];
    const float* h1f3w = (const float*)d_in[33]; const float* h1f3b = (const float*)d_in[34];
    const float* h1f4w = (const float*)d_in[35]; const float* h1f4b = (const float*)d_in[36];
    const float* polw  = (const float*)d_in[37]; const float* polb  = (const float*)d_in[38];
    const float* valw  = (const float*)d_in[39]; const float* valb  = (const float*)d_in[40];

    float* wsf = (float*)d_ws;

    const size_t NEED_BYTES = (size_t)27271168 * 4;
    if (ws_size < NEED_BYTES) {
        sentinel_k<<<1, 128, 0, stream>>>(out);
        return;
    }

    float* scale = wsf + 0;        float* shift = wsf + 256;
    float* ee0 = wsf + 512;        float* ee1 = wsf + 1024;   float* ee2 = wsf + 1536;
    float* cm0 = wsf + 2048;       float* cm1 = wsf + 2112;   float* cm2 = wsf + 2176;
    int*   k0i = (int*)(wsf + 4096);
    int*   k1i = (int*)(wsf + 50304);
    int*   k2i = (int*)(wsf + 51328);
    float* h1a  = wsf + 53248;
    float* ze1f = wsf + 86016;
    float* zq1f = wsf + 151552;
    float* h2a  = wsf + 217088;
    float* ze2f = wsf + 233472;
    float* zq2f = wsf + 299008;
    float* h2b  = wsf + 364544;
    float* decf = wsf + 380928;
    float* x1f  = wsf + 446464;
    float* h1b  = wsf + 512000;
    float* polf = wsf + 544768;
    float* valf = wsf + 591104;

    float* A    = wsf + 655360;
    float* B    = wsf + 12484608;
    float* C64  = wsf + 24313856;
    float* ze0f = A;
    float* zq0f = wsf + 655360 + 1572864;
    float* dec0 = wsf + 655360 + 3145728;
    float* xf   = wsf + 655360 + 4718592;
    float* part = B;

    const int TOT256 = 128 * 256 * 361;
    const int TOT32  = 128 * 32 * 361;
    const int TOT64  = 128 * 64 * 361;

    prep_k<<<4, 512, 0, stream>>>(E0, E1, E2, ee0, ee1, ee2, cm0, cm1, cm2);

    // ---- trunk ----
    conv3x3_k<18, 32, 6><<<dim3(128, 8), 384, 0, stream>>>(obs, c0w, A, 256);
    bnstats_k<<<256, 256, 0, stream>>>(A, bn0g, bn0b, scale, shift, 256);
    bn_relu_k<<<1024, 256, 0, stream>>>(A, scale, shift, 256, TOT256);

    for (int i = 0; i < 3; i++) {
        conv3x3_k<256, 32, 8><<<dim3(128, 8), 384, 0, stream>>>(A, rb1w + (i64)i * 589824, B, 256);
        bnstats_k<<<256, 256, 0, stream>>>(B, rbn1g + i * 256, rbn1b + i * 256, scale, shift, 256);
        bn_relu_k<<<1024, 256, 0, stream>>>(B, scale, shift, 256, TOT256);
        for (int c = 0; c < 4; c++) {
            conv3x3_k<256, 32, 8><<<dim3(128, 2), 384, 0, stream>>>(
                B, rb2w + (i64)i * 589824 + (i64)c * 64 * 256 * 9, C64, 64);
            bnstats_k<<<64, 256, 0, stream>>>(C64, rbn2g + i * 256 + c * 64,
                                              rbn2b + i * 256 + c * 64, scale, shift, 64);
            bn_add_relu_slice_k<<<1024, 256, 0, stream>>>(A, C64, scale, shift, c * 64, TOT64);
        }
    }

    conv3x3_k<256, 16, 8><<<dim3(128, 2), 384, 0, stream>>>(A, c2w, C64, 32);
    bnstats_k<<<32, 256, 0, stream>>>(C64, bn2g, bn2b, scale, shift, 32);
    bn_tanh_ws_k<<<1024, 256, 0, stream>>>(C64, scale, shift, ze0f, TOT32);

    vq0_k<<<181, 256, 0, stream>>>(ze0f, E0, ee0, zq0f, k0i);

    gemm_part_k<<<dim3(4, 32), 256, 0, stream>>>(ze0f, fc1w, part, 11552, 256, 361);
    combine_k<<<128, 256, 0, stream>>>(part, fc1b, h1a, 128 * 256, 256, 32, 1);
    gemm_part_k<<<dim3(8, 4), 256, 0, stream>>>(h1a, fc2w, part, 256, 512, 64);
    combine_k<<<256, 256, 0, stream>>>(part, fc2b, ze1f, 128 * 512, 512, 4, 2);
    vq64_k<<<4, 256, 0, stream>>>(ze1f, E1, ee1, zq1f, k1i);

    gemm_part_k<<<dim3(2, 8), 256, 0, stream>>>(ze1f, h2fw, part, 512, 128, 64);
    combine_k<<<64, 256, 0, stream>>>(part, h2fb, h2a, 128 * 128, 128, 8, 1);
    gemm_part_k<<<dim3(8, 2), 256, 0, stream>>>(h2a, h2f2w, part, 128, 512, 64);
    combine_k<<<256, 256, 0, stream>>>(part, h2f2b, ze2f, 128 * 512, 512, 2, 2);
    vq64_k<<<4, 256, 0, stream>>>(ze2f, E2, ee2, zq2f, k2i);

    gemm_part_k<<<dim3(2, 8), 256, 0, stream>>>(zq2f, h2f3w, part, 512, 128, 64);
    combine_k<<<64, 256, 0, stream>>>(part, h2f3b, h2b, 128 * 128, 128, 8, 1);
    gemm_part_k<<<dim3(8, 2), 256, 0, stream>>>(h2b, h2f4w, part, 128, 512, 64);
    combine_k<<<256, 256, 0, stream>>>(part, h2f4b, decf, 128 * 512, 512, 2, 2);
    blend_k<<<256, 256, 0, stream>>>(zq1f, decf, hier, 1, x1f, 512, 65536);

    gemm_part_k<<<dim3(4, 8), 256, 0, stream>>>(x1f, h1f3w, part, 512, 256, 64);
    combine_k<<<128, 256, 0, stream>>>(part, h1f3b, h1b, 128 * 256, 256, 8, 1);
    gemm_part_k<<<dim3(181, 2), 256, 0, stream>>>(h1b, h1f4w, part, 256, 11552, 128);
    combine_k<<<1024, 256, 0, stream>>>(part, h1f4b, dec0, TOT32, 11552, 2, 2);
    blend_k<<<1024, 256, 0, stream>>>(zq0f, dec0, hier, 0, xf, 11552, TOT32);

    gemm_part_k<<<dim3(6, 16), 256, 0, stream>>>(xf, polw, part, 11552, 362, 722);
    combine_k<<<256, 256, 0, stream>>>(part, polb, polf, 128 * 362, 362, 16, 0);
    value_k<<<128, 256, 0, stream>>>(xf, valw, valb, valf);

    // ---- emit phase: d_out is float32 ----
    emit_f32_k<<<128, 256, 0, stream>>>(polf, out, OUT_POLICY, 46336);
    emit_f32_k<<<1, 128, 0, stream>>>(valf, out, OUT_VALUE, 128);
    emit_f32_k<<<1024, 256, 0, stream>>>(ze0f, out, OUT_ZE0, TOT32);
    emit_f32_k<<<256, 256, 0, stream>>>(ze1f, out, OUT_ZE1, 65536);
    emit_f32_k<<<256, 256, 0, stream>>>(ze2f, out, OUT_ZE2, 65536);
    emit_f32_k<<<1024, 256, 0, stream>>>(zq0f, out, OUT_ZQ0, TOT32);
    emit_f32_k<<<256, 256, 0, stream>>>(zq1f, out, OUT_ZQ1, 65536);
    emit_f32_k<<<256, 256, 0, stream>>>(zq2f, out, OUT_ZQ2, 65536);
    emit_k_k<<<181, 256, 0, stream>>>(k0i, out, OUT_K0, 46208);
    emit_k_k<<<4, 256, 0, stream>>>(k1i, out, OUT_K1, 1024);
    emit_k_k<<<4, 256, 0, stream>>>(k2i, out, OUT_K2, 1024);
    emit_f32_k<<<1024, 256, 0, stream>>>(zq0f, out, OUT_ZQL0, TOT32);
    emit_f32_k<<<256, 256, 0, stream>>>(zq1f, out, OUT_ZQL1, 65536);
    emit_f32_k<<<256, 256, 0, stream>>>(zq2f, out, OUT_ZQL2, 65536);
    emit_em_k<<<1024, 256, 0, stream>>>(cm0, out, OUT_EM0, 32, 361, TOT32);
    emit_em_k<<<256, 256, 0, stream>>>(cm1, out, OUT_EM1, 64, 8, 65536);
    emit_em_k<<<256, 256, 0, stream>>>(cm2, out, OUT_EM2, 64, 8, 65536);
}

// Round 6
// 15699.648 us; speedup vs baseline: 1.3147x; 1.3147x over previous
//
#include <hip/hip_runtime.h>
#include <hip/hip_bf16.h>

typedef long long i64;

// ---- output element offsets (FLOAT32 elements — d_out is float*) ----
static constexpr i64 OUT_POLICY = 0;
static constexpr i64 OUT_VALUE  = 46336;
static constexpr i64 OUT_ZE0    = 46464;
static constexpr i64 OUT_ZE1    = 1525120;
static constexpr i64 OUT_ZE2    = 1590656;
static constexpr i64 OUT_ZQ0    = 1656192;
static constexpr i64 OUT_ZQ1    = 3134848;
static constexpr i64 OUT_ZQ2    = 3200384;
static constexpr i64 OUT_K0     = 3265920;
static constexpr i64 OUT_K1     = 3312128;
static constexpr i64 OUT_K2     = 3313152;
static constexpr i64 OUT_ZQL0   = 3314176;
static constexpr i64 OUT_ZQL1   = 4792832;
static constexpr i64 OUT_ZQL2   = 4858368;
static constexpr i64 OUT_EM0    = 4923904;
static constexpr i64 OUT_EM1    = 6402560;
static constexpr i64 OUT_EM2    = 6468096;
static constexpr i64 OUT_TOTAL  = 6533632;

// =============== conv 3x3 SAME, NCHW, f32, no bias (BN cancels it) ===============
// 16 output channels per block, NAMED scalar accumulators (no arrays -> no scratch).
template<int CIN, int CHUNK>
__global__ __launch_bounds__(384)
void conv3x3_k(const float* __restrict__ in, const float* __restrict__ w,
               float* __restrict__ out, int cout)
{
    __shared__ float tile[CHUNK][441];
    const int n   = blockIdx.x;
    const int co0 = blockIdx.y * 16;
    const int tid = threadIdx.x;
    const bool act = tid < 361;
    const int y = tid / 19, x = tid % 19;
    const int base = y * 21 + x;

    float a0=0.f,a1=0.f,a2=0.f,a3=0.f,a4=0.f,a5=0.f,a6=0.f,a7=0.f;
    float a8=0.f,a9=0.f,a10=0.f,a11=0.f,a12=0.f,a13=0.f,a14=0.f,a15=0.f;

    for (int ci0 = 0; ci0 < CIN; ci0 += CHUNK) {
        __syncthreads();
        for (int i = tid; i < CHUNK * 441; i += 384) {
            int p = i / 441, r = i - p * 441;
            int yy = r / 21, xx = r - yy * 21;
            int iy = yy - 1, ix = xx - 1;
            float v = 0.f;
            if (iy >= 0 && iy < 19 && ix >= 0 && ix < 19)
                v = in[((i64)n * CIN + ci0 + p) * 361 + iy * 19 + ix];
            tile[p][r] = v;
        }
        __syncthreads();
        if (act) {
#pragma unroll 1
            for (int p = 0; p < CHUNK; p++) {
                const float* tp = &tile[p][base];
                float t0 = tp[0],  t1 = tp[1],  t2 = tp[2];
                float t3 = tp[21], t4 = tp[22], t5 = tp[23];
                float t6 = tp[42], t7 = tp[43], t8 = tp[44];
                const float* wp = w + ((i64)co0 * CIN + ci0 + p) * 9;
#define DO_CO(A, I) { const float* wq = wp + (i64)(I) * CIN * 9;                         \
                A = fmaf(t0, wq[0], A); A = fmaf(t1, wq[1], A); A = fmaf(t2, wq[2], A);  \
                A = fmaf(t3, wq[3], A); A = fmaf(t4, wq[4], A); A = fmaf(t5, wq[5], A);  \
                A = fmaf(t6, wq[6], A); A = fmaf(t7, wq[7], A); A = fmaf(t8, wq[8], A); }
                DO_CO(a0, 0)  DO_CO(a1, 1)  DO_CO(a2, 2)  DO_CO(a3, 3)
                DO_CO(a4, 4)  DO_CO(a5, 5)  DO_CO(a6, 6)  DO_CO(a7, 7)
                DO_CO(a8, 8)  DO_CO(a9, 9)  DO_CO(a10,10) DO_CO(a11,11)
                DO_CO(a12,12) DO_CO(a13,13) DO_CO(a14,14) DO_CO(a15,15)
#undef DO_CO
            }
        }
    }
    if (act) {
        float* op = out + ((i64)n * cout + co0) * 361 + tid;
        op[0*361]=a0;  op[1*361]=a1;  op[2*361]=a2;  op[3*361]=a3;
        op[4*361]=a4;  op[5*361]=a5;  op[6*361]=a6;  op[7*361]=a7;
        op[8*361]=a8;  op[9*361]=a9;  op[10*361]=a10; op[11*361]=a11;
        op[12*361]=a12; op[13*361]=a13; op[14*361]=a14; op[15*361]=a15;
    }
}

// =============== BN batch-stats -> scale/shift ===============
__global__ __launch_bounds__(256)
void bnstats_k(const float* __restrict__ x, const float* __restrict__ g,
               const float* __restrict__ b, float* __restrict__ scale,
               float* __restrict__ shift, int C)
{
    const int c = blockIdx.x;
    float s = 0.f, s2 = 0.f;
    for (int n = 0; n < 128; n++) {
        const float* p = x + ((i64)n * C + c) * 361;
        for (int i = threadIdx.x; i < 361; i += 256) {
            float v = p[i]; s += v; s2 += v * v;
        }
    }
    __shared__ float rs[4], rq[4];
    for (int o = 32; o > 0; o >>= 1) { s += __shfl_down(s, o); s2 += __shfl_down(s2, o); }
    int lane = threadIdx.x & 63, wid = threadIdx.x >> 6;
    if (lane == 0) { rs[wid] = s; rq[wid] = s2; }
    __syncthreads();
    if (threadIdx.x == 0) {
        float S = rs[0] + rs[1] + rs[2] + rs[3];
        float Q = rq[0] + rq[1] + rq[2] + rq[3];
        const float inv = 1.f / 46208.f;
        float m  = S * inv;
        float var = Q * inv - m * m;
        float sc = g[c] * rsqrtf(var + 1e-5f);
        scale[c] = sc;
        shift[c] = b[c] - m * sc;
    }
}

// =============== BN apply variants (ws-only) ===============
__global__ void bn_relu_k(float* __restrict__ x, const float* __restrict__ scale,
                          const float* __restrict__ shift, int C, int total)
{
    for (int i = blockIdx.x * blockDim.x + threadIdx.x; i < total; i += gridDim.x * blockDim.x) {
        int c = (i / 361) % C;
        float v = fmaf(x[i], scale[c], shift[c]);
        x[i] = v > 0.f ? v : 0.f;
    }
}

__global__ void bn_add_relu_slice_k(float* __restrict__ xa, const float* __restrict__ xc,
                                    const float* __restrict__ scale, const float* __restrict__ shift,
                                    int cbase, int total)
{
    for (int i = blockIdx.x * blockDim.x + threadIdx.x; i < total; i += gridDim.x * blockDim.x) {
        int s = i % 361;
        int t = i / 361;
        int ch = t % 64;
        int n = t / 64;
        i64 ai = ((i64)n * 256 + cbase + ch) * 361 + s;
        float v = xa[ai] + fmaf(xc[i], scale[ch], shift[ch]);
        xa[ai] = v > 0.f ? v : 0.f;
    }
}

__global__ void bn_tanh_ws_k(const float* __restrict__ x, const float* __restrict__ scale,
                             const float* __restrict__ shift, float* __restrict__ zf, int total)
{
    for (int i = blockIdx.x * blockDim.x + threadIdx.x; i < total; i += gridDim.x * blockDim.x) {
        int c = (i / 361) & 31;
        zf[i] = tanhf(fmaf(x[i], scale[c], shift[c]));
    }
}

// =============== codebook prep ===============
__global__ void prep_k(const float* __restrict__ E0, const float* __restrict__ E1,
                       const float* __restrict__ E2,
                       float* __restrict__ ee0, float* __restrict__ ee1, float* __restrict__ ee2,
                       float* __restrict__ cm0, float* __restrict__ cm1, float* __restrict__ cm2)
{
    int t = threadIdx.x;
    if (blockIdx.x == 0) {
        float s = 0.f; const float* e = E0 + (i64)t * 32;
        for (int d = 0; d < 32; d++) s += e[d] * e[d];
        ee0[t] = s;
    } else if (blockIdx.x == 1) {
        float s = 0.f; const float* e = E1 + (i64)t * 64;
        for (int d = 0; d < 64; d++) s += e[d] * e[d];
        ee1[t] = s;
    } else if (blockIdx.x == 2) {
        float s = 0.f; const float* e = E2 + (i64)t * 64;
        for (int d = 0; d < 64; d++) s += e[d] * e[d];
        ee2[t] = s;
    } else {
        if (t < 32) {
            float s = 0.f; for (int k = 0; k < 512; k++) s += E0[k * 32 + t];
            cm0[t] = s * (1.f / 512.f);
        } else if (t >= 64 && t < 128) {
            int d = t - 64; float s = 0.f; for (int k = 0; k < 512; k++) s += E1[k * 64 + d];
            cm1[d] = s * (1.f / 512.f);
        } else if (t >= 128 && t < 192) {
            int d = t - 128; float s = 0.f; for (int k = 0; k < 512; k++) s += E2[k * 64 + d];
            cm2[d] = s * (1.f / 512.f);
        }
    }
}

// =============== VQ kernels (32 KB LDS, multi-pass staging) ===============
__global__ __launch_bounds__(256)
void vq0_k(const float* __restrict__ z, const float* __restrict__ E,
           const float* __restrict__ ee, float* __restrict__ zqf, int* __restrict__ ki)
{
    __shared__ float Es[256 * 32];
    int row = blockIdx.x * 256 + threadIdx.x;
    const bool live = row < 46208;
    const float* zp = z + (i64)(live ? row : 0) * 32;
    float zv[32]; float zz = 0.f;
#pragma unroll
    for (int d = 0; d < 32; d++) { float v = zp[d]; zv[d] = v; zz += v * v; }
    float best = 3.4e38f; int bk = 0;
    for (int h = 0; h < 2; h++) {
        __syncthreads();
        for (int i = threadIdx.x; i < 256 * 32; i += 256) Es[i] = E[h * 8192 + i];
        __syncthreads();
        for (int k = 0; k < 256; k++) {
            const float* e = Es + k * 32;
            float dot = 0.f;
#pragma unroll
            for (int d = 0; d < 32; d++) dot = fmaf(zv[d], e[d], dot);
            float dist = (zz + ee[h * 256 + k]) - 2.f * dot;
            if (dist < best) { best = dist; bk = h * 256 + k; }
        }
    }
    if (live) {
        ki[row] = bk;
        const float* eb = E + (i64)bk * 32;
#pragma unroll
        for (int d = 0; d < 32; d++) zqf[(i64)row * 32 + d] = eb[d];
    }
}

__global__ __launch_bounds__(256)
void vq64_k(const float* __restrict__ z, const float* __restrict__ E,
            const float* __restrict__ ee, float* __restrict__ zqf, int* __restrict__ ki)
{
    __shared__ float Es[128 * 64];
    int row = blockIdx.x * 256 + threadIdx.x;
    const float* zp = z + (i64)row * 64;
    float zv[64]; float zz = 0.f;
#pragma unroll
    for (int d = 0; d < 64; d++) { float v = zp[d]; zv[d] = v; zz += v * v; }
    float best = 3.4e38f; int bk = 0;
    for (int h = 0; h < 4; h++) {
        __syncthreads();
        for (int i = threadIdx.x; i < 128 * 64; i += 256) Es[i] = E[(i64)h * 8192 + i];
        __syncthreads();
        for (int k = 0; k < 128; k++) {
            const float* e = Es + k * 64;
            float dot = 0.f;
#pragma unroll
            for (int d = 0; d < 64; d++) dot = fmaf(zv[d], e[d], dot);
            float dist = (zz + ee[h * 128 + k]) - 2.f * dot;
            if (dist < best) { best = dist; bk = h * 128 + k; }
        }
    }
    ki[row] = bk;
    const float* eb = E + (i64)bk * 64;
#pragma unroll
    for (int d = 0; d < 64; d++) zqf[(i64)row * 64 + d] = eb[d];
}

// =============== split-K GEMM ===============
__global__ __launch_bounds__(256)
void gemm_part_k(const float* __restrict__ A, const float* __restrict__ W,
                 float* __restrict__ part, int K, int N, int kchunk)
{
    __shared__ float As[128][17];
    __shared__ float Ws[16][64];
    const int n0 = blockIdx.x * 64;
    const int ks = blockIdx.y;
    const int kb0  = ks * kchunk;
    const int kend = min(K, kb0 + kchunk);
    const int tid = threadIdx.x;
    const int tn = tid & 15, tm = tid >> 4;
    float acc[8][4];
#pragma unroll
    for (int i = 0; i < 8; i++)
#pragma unroll
        for (int j = 0; j < 4; j++) acc[i][j] = 0.f;

    for (int kb = kb0; kb < kend; kb += 16) {
        __syncthreads();
        for (int i = tid; i < 2048; i += 256) {
            int m = i >> 4, kk = i & 15;
            int k = kb + kk;
            As[m][kk] = (k < kend) ? A[(i64)m * K + k] : 0.f;
        }
        for (int i = tid; i < 1024; i += 256) {
            int kk = i >> 6, nl = i & 63;
            int k = kb + kk, n = n0 + nl;
            Ws[kk][nl] = (k < kend && n < N) ? W[(i64)k * N + n] : 0.f;
        }
        __syncthreads();
#pragma unroll
        for (int kk = 0; kk < 16; kk++) {
            float av[8], wv[4];
#pragma unroll
            for (int i = 0; i < 8; i++) av[i] = As[tm * 8 + i][kk];
#pragma unroll
            for (int j = 0; j < 4; j++) wv[j] = Ws[kk][tn * 4 + j];
#pragma unroll
            for (int i = 0; i < 8; i++)
#pragma unroll
                for (int j = 0; j < 4; j++) acc[i][j] = fmaf(av[i], wv[j], acc[i][j]);
        }
    }
#pragma unroll
    for (int i = 0; i < 8; i++) {
        int m = tm * 8 + i;
#pragma unroll
        for (int j = 0; j < 4; j++) {
            int n = n0 + tn * 4 + j;
            if (n < N) part[((i64)ks * 128 + m) * N + n] = acc[i][j];
        }
    }
}

__global__ void combine_k(const float* __restrict__ part, const float* __restrict__ bias,
                          float* __restrict__ of, int MN, int N, int ksplit, int act)
{
    for (int i = blockIdx.x * blockDim.x + threadIdx.x; i < MN; i += gridDim.x * blockDim.x) {
        float s = 0.f;
        for (int t = 0; t < ksplit; t++) s += part[(i64)t * MN + i];
        s += bias[i % N];
        if (act == 1) s = s > 0.f ? s : 0.f;
        else if (act == 2) s = tanhf(s);
        of[i] = s;
    }
}

__global__ void blend_k(const float* __restrict__ q, const float* __restrict__ d,
                        const float* __restrict__ hu, int col, float* __restrict__ o,
                        int per_b, int total)
{
    for (int i = blockIdx.x * blockDim.x + threadIdx.x; i < total; i += gridDim.x * blockDim.x) {
        float u = hu[(i / per_b) * 2 + col];
        o[i] = u * q[i] + (1.f - u) * d[i];
    }
}

__global__ __launch_bounds__(256)
void value_k(const float* __restrict__ x, const float* __restrict__ w,
             const float* __restrict__ b, float* __restrict__ valf)
{
    int m = blockIdx.x;
    float s = 0.f;
    const float* xp = x + (i64)m * 11552;
    for (int k = threadIdx.x; k < 11552; k += 256) s = fmaf(xp[k], w[k], s);
    for (int o = 32; o > 0; o >>= 1) s += __shfl_down(s, o);
    __shared__ float r[4];
    int lane = threadIdx.x & 63, wid = threadIdx.x >> 6;
    if (lane == 0) r[wid] = s;
    __syncthreads();
    if (threadIdx.x == 0)
        valf[m] = tanhf(r[0] + r[1] + r[2] + r[3] + b[0]);
}

// =============== emit phase (d_out is FLOAT32) ===============
__global__ void emit_f32_k(const float* __restrict__ src, float* __restrict__ out, i64 off, int n)
{
    for (int i = blockIdx.x * blockDim.x + threadIdx.x; i < n; i += gridDim.x * blockDim.x)
        out[off + i] = src[i];
}

__global__ void emit_k_k(const int* __restrict__ ki, float* __restrict__ out, i64 off, int n)
{
    for (int i = blockIdx.x * blockDim.x + threadIdx.x; i < n; i += gridDim.x * blockDim.x)
        out[off + i] = (float)ki[i];
}

__global__ void emit_em_k(const float* __restrict__ cm, float* __restrict__ out, i64 off,
                          int D, int SPL, int total)
{
    for (int i = blockIdx.x * blockDim.x + threadIdx.x; i < total; i += gridDim.x * blockDim.x) {
        int c = (i / SPL) % D;
        out[off + i] = cm[c];
    }
}

// =============== guard markers ===============
__global__ void marker_k(float* __restrict__ out, int code)
{
    if (threadIdx.x < 64) out[threadIdx.x] = 3000.f + 100.f * code;
}

__global__ void sentinel_k(float* __restrict__ out)
{
    if (threadIdx.x < 128) out[OUT_VALUE + threadIdx.x] = 2000.0f;
}

// ===================== host launch =====================
extern "C" void kernel_launch(void* const* d_in, const int* in_sizes, int n_in,
                              void* d_out, int out_size, void* d_ws, size_t ws_size,
                              hipStream_t stream)
{
    float* out = (float*)d_out;

    int bad = -1;
    if (out_size != (int)OUT_TOTAL) bad = 0;
    else if (n_in != 41) bad = 1;
    else if (in_sizes[0] != 128 * 18 * 361) bad = 2;
    else if (in_sizes[21] != 11552 * 256) bad = 3;
    if (bad >= 0) { marker_k<<<1, 64, 0, stream>>>(out, bad); return; }

    const float* obs   = (const float*)d_in[0];
    const float* hier  = (const float*)d_in[1];
    const float* c0w   = (const float*)d_in[2];
    const float* bn0g  = (const float*)d_in[4];
    const float* bn0b  = (const float*)d_in[5];
    const float* rb1w  = (const float*)d_in[6];
    const float* rbn1g = (const float*)d_in[8];
    const float* rbn1b = (const float*)d_in[9];
    const float* rb2w  = (const float*)d_in[10];
    const float* rbn2g = (const float*)d_in[12];
    const float* rbn2b = (const float*)d_in[13];
    const float* c2w   = (const float*)d_in[14];
    const float* bn2g  = (const float*)d_in[16];
    const float* bn2b  = (const float*)d_in[17];
    const float* E0    = (const float*)d_in[18];
    const float* E1    = (const float*)d_in[19];
    const float* E2    = (const float*)d_in[20];
    const float* fc1w  = (const float*)d_in[21]; const float* fc1b  = (const float*)d_in[22];
    const float* fc2w  = (const float*)d_in[23]; const float* fc2b  = (const float*)d_in[24];
    const float* h2fw  = (const float*)d_in[25]; const float* h2fb  = (const float*)d_in[26];
    const float* h2f2w = (const float*)d_in[27]; const float* h2f2b = (const float*)d_in[28];
    const float* h2f3w = (const float*)d_in[29]; const float* h2f3b = (const float*)d_in[30];
    const float* h2f4w = (const float*)d_in[31]; const float* h2f4b = (const float*)d_in[32];
    const float* h1f3w = (const float*)d_in[33]; const float* h1f3b = (const float*)d_in[34];
    const float* h1f4w = (const float*)d_in[35]; const float* h1f4b = (const float*)d_in[36];
    const float* polw  = (const float*)d_in[37]; const float* polb  = (const float*)d_in[38];
    const float* valw  = (const float*)d_in[39]; const float* valb  = (const float*)d_in[40];

    float* wsf = (float*)d_ws;

    const size_t NEED_BYTES = (size_t)27271168 * 4;
    if (ws_size < NEED_BYTES) {
        sentinel_k<<<1, 128, 0, stream>>>(out);
        return;
    }

    float* scale = wsf + 0;        float* shift = wsf + 256;
    float* ee0 = wsf + 512;        float* ee1 = wsf + 1024;   float* ee2 = wsf + 1536;
    float* cm0 = wsf + 2048;       float* cm1 = wsf + 2112;   float* cm2 = wsf + 2176;
    int*   k0i = (int*)(wsf + 4096);
    int*   k1i = (int*)(wsf + 50304);
    int*   k2i = (int*)(wsf + 51328);
    float* h1a  = wsf + 53248;
    float* ze1f = wsf + 86016;
    float* zq1f = wsf + 151552;
    float* h2a  = wsf + 217088;
    float* ze2f = wsf + 233472;
    float* zq2f = wsf + 299008;
    float* h2b  = wsf + 364544;
    float* decf = wsf + 380928;
    float* x1f  = wsf + 446464;
    float* h1b  = wsf + 512000;
    float* polf = wsf + 544768;
    float* valf = wsf + 591104;

    float* A    = wsf + 655360;
    float* B    = wsf + 12484608;
    float* C64  = wsf + 24313856;
    float* ze0f = A;
    float* zq0f = wsf + 655360 + 1572864;
    float* dec0 = wsf + 655360 + 3145728;
    float* xf   = wsf + 655360 + 4718592;
    float* part = B;

    const int TOT256 = 128 * 256 * 361;
    const int TOT32  = 128 * 32 * 361;
    const int TOT64  = 128 * 64 * 361;

    prep_k<<<4, 512, 0, stream>>>(E0, E1, E2, ee0, ee1, ee2, cm0, cm1, cm2);

    // ---- trunk ----
    conv3x3_k<18, 6><<<dim3(128, 16), 384, 0, stream>>>(obs, c0w, A, 256);
    bnstats_k<<<256, 256, 0, stream>>>(A, bn0g, bn0b, scale, shift, 256);
    bn_relu_k<<<1024, 256, 0, stream>>>(A, scale, shift, 256, TOT256);

    for (int i = 0; i < 3; i++) {
        conv3x3_k<256, 8><<<dim3(128, 16), 384, 0, stream>>>(A, rb1w + (i64)i * 589824, B, 256);
        bnstats_k<<<256, 256, 0, stream>>>(B, rbn1g + i * 256, rbn1b + i * 256, scale, shift, 256);
        bn_relu_k<<<1024, 256, 0, stream>>>(B, scale, shift, 256, TOT256);
        for (int c = 0; c < 4; c++) {
            conv3x3_k<256, 8><<<dim3(128, 4), 384, 0, stream>>>(
                B, rb2w + (i64)i * 589824 + (i64)c * 64 * 256 * 9, C64, 64);
            bnstats_k<<<64, 256, 0, stream>>>(C64, rbn2g + i * 256 + c * 64,
                                              rbn2b + i * 256 + c * 64, scale, shift, 64);
            bn_add_relu_slice_k<<<1024, 256, 0, stream>>>(A, C64, scale, shift, c * 64, TOT64);
        }
    }

    conv3x3_k<256, 8><<<dim3(128, 2), 384, 0, stream>>>(A, c2w, C64, 32);
    bnstats_k<<<32, 256, 0, stream>>>(C64, bn2g, bn2b, scale, shift, 32);
    bn_tanh_ws_k<<<1024, 256, 0, stream>>>(C64, scale, shift, ze0f, TOT32);

    vq0_k<<<181, 256, 0, stream>>>(ze0f, E0, ee0, zq0f, k0i);

    gemm_part_k<<<dim3(4, 32), 256, 0, stream>>>(ze0f, fc1w, part, 11552, 256, 361);
    combine_k<<<128, 256, 0, stream>>>(part, fc1b, h1a, 128 * 256, 256, 32, 1);
    gemm_part_k<<<dim3(8, 4), 256, 0, stream>>>(h1a, fc2w, part, 256, 512, 64);
    combine_k<<<256, 256, 0, stream>>>(part, fc2b, ze1f, 128 * 512, 512, 4, 2);
    vq64_k<<<4, 256, 0, stream>>>(ze1f, E1, ee1, zq1f, k1i);

    gemm_part_k<<<dim3(2, 8), 256, 0, stream>>>(ze1f, h2fw, part, 512, 128, 64);
    combine_k<<<64, 256, 0, stream>>>(part, h2fb, h2a, 128 * 128, 128, 8, 1);
    gemm_part_k<<<dim3(8, 2), 256, 0, stream>>>(h2a, h2f2w, part, 128, 512, 64);
    combine_k<<<256, 256, 0, stream>>>(part, h2f2b, ze2f, 128 * 512, 512, 2, 2);
    vq64_k<<<4, 256, 0, stream>>>(ze2f, E2, ee2, zq2f, k2i);

    gemm_part_k<<<dim3(2, 8), 256, 0, stream>>>(zq2f, h2f3w, part, 512, 128, 64);
    combine_k<<<64, 256, 0, stream>>>(part, h2f3b, h2b, 128 * 128, 128, 8, 1);
    gemm_part_k<<<dim3(8, 2), 256, 0, stream>>>(h2b, h2f4w, part, 128, 512, 64);
    combine_k<<<256, 256, 0, stream>>>(part, h2f4b, decf, 128 * 512, 512, 2, 2);
    blend_k<<<256, 256, 0, stream>>>(zq1f, decf, hier, 1, x1f, 512, 65536);

    gemm_part_k<<<dim3(4, 8), 256, 0, stream>>>(x1f, h1f3w, part, 512, 256, 64);
    combine_k<<<128, 256, 0, stream>>>(part, h1f3b, h1b, 128 * 256, 256, 8, 1);
    gemm_part_k<<<dim3(181, 2), 256, 0, stream>>>(h1b, h1f4w, part, 256, 11552, 128);
    combine_k<<<1024, 256, 0, stream>>>(part, h1f4b, dec0, TOT32, 11552, 2, 2);
    blend_k<<<1024, 256, 0, stream>>>(zq0f, dec0, hier, 0, xf, 11552, TOT32);

    gemm_part_k<<<dim3(6, 16), 256, 0, stream>>>(xf, polw, part, 11552, 362, 722);
    combine_k<<<256, 256, 0, stream>>>(part, polb, polf, 128 * 362, 362, 16, 0);
    value_k<<<128, 256, 0, stream>>>(xf, valw, valb, valf);

    // ---- emit phase: d_out is float32 ----
    emit_f32_k<<<128, 256, 0, stream>>>(polf, out, OUT_POLICY, 46336);
    emit_f32_k<<<1, 128, 0, stream>>>(valf, out, OUT_VALUE, 128);
    emit_f32_k<<<1024, 256, 0, stream>>>(ze0f, out, OUT_ZE0, TOT32);
    emit_f32_k<<<256, 256, 0, stream>>>(ze1f, out, OUT_ZE1, 65536);
    emit_f32_k<<<256, 256, 0, stream>>>(ze2f, out, OUT_ZE2, 65536);
    emit_f32_k<<<1024, 256, 0, stream>>>(zq0f, out, OUT_ZQ0, TOT32);
    emit_f32_k<<<256, 256, 0, stream>>>(zq1f, out, OUT_ZQ1, 65536);
    emit_f32_k<<<256, 256, 0, stream>>>(zq2f, out, OUT_ZQ2, 65536);
    emit_k_k<<<181, 256, 0, stream>>>(k0i, out, OUT_K0, 46208);
    emit_k_k<<<4, 256, 0, stream>>>(k1i, out, OUT_K1, 1024);
    emit_k_k<<<4, 256, 0, stream>>>(k2i, out, OUT_K2, 1024);
    emit_f32_k<<<1024, 256, 0, stream>>>(zq0f, out, OUT_ZQL0, TOT32);
    emit_f32_k<<<256, 256, 0, stream>>>(zq1f, out, OUT_ZQL1, 65536);
    emit_f32_k<<<256, 256, 0, stream>>>(zq2f, out, OUT_ZQL2, 65536);
    emit_em_k<<<1024, 256, 0, stream>>>(cm0, out, OUT_EM0, 32, 361, TOT32);
    emit_em_k<<<256, 256, 0, stream>>>(cm1, out, OUT_EM1, 64, 8, 65536);
    emit_em_k<<<256, 256, 0, stream>>>(cm2, out, OUT_EM2, 64, 8, 65536);
}